// Round 15
// baseline (576.221 us; speedup 1.0000x reference)
//
#include <hip/hip_runtime.h>
#include <hip/hip_bf16.h>
#include <math.h>

// Problem constants
#define NN 32768          // Dd*Hh*Ww tokens per batch
#define CC 256
#define EE 6
#define HID 1024
#define TT 64             // tokens per tile
#define NTOK 65536        // B * NN
#define NTILE_MAX 1044    // bucket path tiles
#define NT3MAX 3078       // expert-major 64-row tiles
#define NCH 16            // h-chunks per tile (64 h each)
#define SENT 0xFFFFFFFFu

typedef __attribute__((ext_vector_type(8))) short bf16x8;
typedef __attribute__((ext_vector_type(4))) float f32x4;
typedef __attribute__((ext_vector_type(2))) float f32x2;
typedef __attribute__((ext_vector_type(4))) unsigned int u32x4;
typedef __attribute__((ext_vector_type(2))) unsigned int u32x2;

// lexicographic 3-subsets of {0..5}
__device__ const int CMB[20][3] = {
  {0,1,2},{0,1,3},{0,1,4},{0,1,5},{0,2,3},{0,2,4},{0,2,5},{0,3,4},{0,3,5},{0,4,5},
  {1,2,3},{1,2,4},{1,2,5},{1,3,4},{1,3,5},{1,4,5},{2,3,4},{2,3,5},{2,4,5},{3,4,5}};
// expert-bitmask -> bucket id (255 = invalid)
__device__ const unsigned char M2B[64] = {
  255,255,255,255,255,255,255,  0,
  255,255,255,  1,255,  4, 10,255,
  255,255,255,  2,255,  5, 11,255,
  255,  7, 13,255, 16,255,255,255,
  255,255,255,  3,255,  6, 12,255,
  255,  8, 14,255, 17,255,255,255,
  255,  9, 15,255, 18,255,255,255,
   19,255,255,255,255,255,255,255};

__device__ __forceinline__ unsigned short f32_bf16(float f) {
  unsigned u = __builtin_bit_cast(unsigned, f);
  u += 0x7FFFu + ((u >> 16) & 1u);          // RNE
  return (unsigned short)(u >> 16);
}

__device__ __forceinline__ unsigned cvt_pk_bf16(float lo, float hi) {
  unsigned r;
  asm("v_cvt_pk_bf16_f32 %0, %1, %2" : "=v"(r) : "v"(lo), "v"(hi));
  return r;
}

// tanh-form GELU via sigmoid identity; max abs dev from erf-GELU ~1e-3.
__device__ __forceinline__ float fast_gelu(float v) {
  float s = v * v;
  float a = v * -2.3021181819f;
  float m = a * 0.044715f;
  float nu = __builtin_fmaf(m, s, a);
  float z = __builtin_amdgcn_exp2f(nu);
  return v * __builtin_amdgcn_rcpf(1.0f + z);
}

// async global->LDS, 16B per lane; LDS dest is wave-linear (base + lane*16)
typedef __attribute__((address_space(3))) void lds_void;
typedef __attribute__((address_space(1))) const void glb_void;
__device__ __forceinline__ void gload16(const void* g, void* l) {
  __builtin_amdgcn_global_load_lds((glb_void*)g, (lds_void*)l, 16, 0, 0);
}

// ---------- one-time f32 -> bf16 weight conversion ----------
__global__ void wconv(const float* __restrict__ w1, const float* __restrict__ w2,
                      unsigned short* __restrict__ w1b, unsigned short* __restrict__ w2b) {
  int i = blockIdx.x * 256 + threadIdx.x;
  w1b[i] = f32_bf16(w1[i]);
  w2b[i] = f32_bf16(w2[i]);
}

// ================================================================
// ====================  EXPERT-MAJOR PATH  =======================
// ================================================================

// gating + X packing fused
__global__ __launch_bounds__(256) void gatepack_k(
    const float* __restrict__ x, const float* __restrict__ attn,
    const float* __restrict__ gate_w, const float* __restrict__ gate_b,
    unsigned* __restrict__ setid, float* __restrict__ wsel,
    unsigned* __restrict__ ehist, unsigned char* __restrict__ Xp3) {
  __shared__ float gws[EE * CC];            // 6 KB
  __shared__ unsigned char lx[TT * 512];    // 32 KB linear [t][c*2]
  __shared__ float gred[256 * EE];          // 6 KB
  __shared__ unsigned hist6[EE];

  const int tid = threadIdx.x, lane = tid & 63, wv = tid >> 6;
  const int n0g = blockIdx.x * TT;
  const int bI = n0g >> 15, n0 = n0g & (NN - 1);

  for (int i = tid; i < EE * CC; i += 256) gws[i] = gate_w[i];
  if (tid < EE) hist6[tid] = 0;
  __syncthreads();

  {
    float gp[EE] = {0.f, 0.f, 0.f, 0.f, 0.f, 0.f};
    const size_t xbase = ((size_t)bI * CC + wv * 64) * NN + n0 + lane;
    #pragma unroll 1
    for (int c8 = 0; c8 < 8; ++c8) {
      float xv[8];
      #pragma unroll
      for (int j = 0; j < 8; ++j)
        xv[j] = x[xbase + (size_t)(c8 * 8 + j) * NN];   // coalesced over lanes
      #pragma unroll
      for (int j = 0; j < 8; ++j) {
        int c = wv * 64 + c8 * 8 + j;
        #pragma unroll
        for (int e = 0; e < EE; ++e) gp[e] = __builtin_fmaf(xv[j], gws[e * CC + c], gp[e]);
      }
      u32x4 pk;
      #pragma unroll
      for (int q = 0; q < 4; ++q) pk[q] = cvt_pk_bf16(xv[2 * q], xv[2 * q + 1]);
      *(u32x4*)(lx + lane * 512 + (wv * 64 + c8 * 8) * 2) = pk;
    }
    #pragma unroll
    for (int e = 0; e < EE; ++e) gred[(wv * 64 + lane) * EE + e] = gp[e];
  }
  __syncthreads();

  if (tid < 64) {
    float g[EE];
    #pragma unroll
    for (int e = 0; e < EE; ++e)
      g[e] = gred[(0 * 64 + tid) * EE + e] + gred[(1 * 64 + tid) * EE + e] +
             gred[(2 * 64 + tid) * EE + e] + gred[(3 * 64 + tid) * EE + e];
    float aw = attn[n0g + tid];
    float m = -1e30f;
    #pragma unroll
    for (int e = 0; e < EE; ++e) { g[e] = (g[e] + gate_b[e]) * aw; m = fmaxf(m, g[e]); }
    float ex[EE], s = 0.f;
    #pragma unroll
    for (int e = 0; e < EE; ++e) { ex[e] = expf(g[e] - m); s += ex[e]; }
    int i1 = 0; float v1 = g[0];
    #pragma unroll
    for (int e = 1; e < EE; ++e) if (g[e] > v1) { v1 = g[e]; i1 = e; }
    int i2 = -1; float v2 = -3.4e38f;
    #pragma unroll
    for (int e = 0; e < EE; ++e) if (e != i1 && g[e] > v2) { v2 = g[e]; i2 = e; }
    int i3 = -1; float v3 = -3.4e38f;
    #pragma unroll
    for (int e = 0; e < EE; ++e) if (e != i1 && e != i2 && g[e] > v3) { v3 = g[e]; i3 = e; }
    const unsigned msk = (1u << i1) | (1u << i2) | (1u << i3);
    float inv = 1.f / s;
    int slot = 0;
    #pragma unroll
    for (int e = 0; e < EE; ++e)
      if ((msk >> e) & 1u) wsel[(size_t)(n0g + tid) * 3 + (slot++)] = ex[e] * inv;
    setid[n0g + tid] = (unsigned)M2B[msk];
    atomicAdd(&hist6[i1], 1u); atomicAdd(&hist6[i2], 1u); atomicAdd(&hist6[i3], 1u);
  }
  __syncthreads();

  #pragma unroll 1
  for (int r = 0; r < 16; ++r) {
    const int t = wv * 16 + r;
    u32x2 v = *(const u32x2*)(lx + t * 512 + lane * 8);
    *(u32x2*)(Xp3 + (size_t)(n0g + t) * 512 + lane * 8) = v;   // 512B/row coalesced
  }
  if (tid < EE) ehist[tid * 1024 + blockIdx.x] = hist6[tid];
}

// ---------- prefix: per-expert bases, 64-row tile descriptors ----------
// desc encoding: [e:31..16][g:15..0]  (g = 64-row group index)
__global__ __launch_bounds__(256) void prefix3_k(
    const unsigned* __restrict__ ehist, unsigned* __restrict__ ebase,
    unsigned* __restrict__ desc3, unsigned* __restrict__ tlist3,
    float* __restrict__ wp3) {
  __shared__ unsigned sc[256];
  __shared__ unsigned tot[EE], bb[EE + 1], tcum[EE + 1];
  const int tid = threadIdx.x;
  #pragma unroll 1
  for (int e = 0; e < EE; ++e) {
    unsigned v[4]; unsigned s = 0;
    #pragma unroll
    for (int k = 0; k < 4; ++k) { v[k] = ehist[e * 1024 + tid * 4 + k]; s += v[k]; }
    sc[tid] = s; __syncthreads();
    for (int off = 1; off < 256; off <<= 1) {
      unsigned tv = (tid >= off) ? sc[tid - off] : 0u; __syncthreads();
      sc[tid] += tv; __syncthreads();
    }
    unsigned excl = sc[tid] - s;
    if (tid == 255) tot[e] = sc[255];
    unsigned run = excl;
    #pragma unroll
    for (int k = 0; k < 4; ++k) { ebase[e * 1024 + tid * 4 + k] = run; run += v[k]; }
    __syncthreads();
  }
  if (tid == 0) {
    unsigned base = 0, tc = 0;
    for (int e = 0; e < EE; ++e) {
      bb[e] = base; tcum[e] = tc;
      unsigned tl = (tot[e] + 63) >> 6;
      tc += tl; base += tl << 6;
    }
    bb[EE] = base; tcum[EE] = tc;
  }
  __syncthreads();
  #pragma unroll 1
  for (int e = 0; e < EE; ++e) {
    unsigned b0 = bb[e];
    #pragma unroll
    for (int k = 0; k < 4; ++k) ebase[e * 1024 + tid * 4 + k] += b0;
  }
  if (tid < EE) {
    for (unsigned i = bb[tid] + tot[tid]; i < bb[tid + 1]; ++i) {
      tlist3[i] = SENT; wp3[i] = 0.f;
    }
  }
  __syncthreads();
  const unsigned nt = tcum[EE];
  for (int i = tid; i < NT3MAX; i += 256) {
    unsigned d;
    if ((unsigned)i < nt) {
      int e = 0;
      while (!((unsigned)i >= tcum[e] && (unsigned)i < tcum[e + 1])) ++e;
      d = ((unsigned)e << 16) | ((bb[e] >> 6) + ((unsigned)i - tcum[e]));
    } else d = 0x003F0000u;
    desc3[i] = d;
  }
}

// ---------- scatter3: token -> 3 expert-list entries (deterministic) ----------
__global__ __launch_bounds__(64) void scatter3_k(
    const unsigned* __restrict__ setid, const unsigned* __restrict__ ebase,
    const float* __restrict__ wsel,
    unsigned* __restrict__ tlist3, float* __restrict__ wp3, unsigned* __restrict__ pos3) {
  const int tid = threadIdx.x;
  const int blk = blockIdx.x;
  const unsigned id = blk * 64 + tid;
  const unsigned bkt = setid[id];
  const unsigned m6 =
      (1u << CMB[bkt][0]) | (1u << CMB[bkt][1]) | (1u << CMB[bkt][2]);
  const unsigned long long below = (1ull << tid) - 1ull;
  int s = 0;
  #pragma unroll
  for (int e = 0; e < EE; ++e) {
    unsigned long long bl = __ballot((m6 >> e) & 1u);
    if ((m6 >> e) & 1u) {
      unsigned rank = (unsigned)__builtin_popcountll(bl & below);
      unsigned p = ebase[e * 1024 + blk] + rank;
      tlist3[p] = id;
      wp3[p] = wsel[(size_t)id * 3 + s];
      pos3[(size_t)id * 3 + s] = p;
      s++;
    }
  }
}

// ---------- main3: K-major async pipeline, 2 barriers/chunk ----------
// R13 base (64-token tile, 512 thr, 16 chunks of 64 h) with:
//  * K-major weight buffers: ws1 [kb8][h64][16B], ws2 [kb8][c256][16B]
//    -> MFMA reads are contiguous 16B/lane, stage addressing trivial.
//  * 2 barriers per chunk: A (lgkm: hs ready, ws1 free) -> STAGE1(k+2)
//    hides under GEMM2 -> vmcnt(4)+B (chunk k+1 resident, ws2 free)
//    -> STAGE2(k+2).
__global__ __launch_bounds__(512, 2) void moe_main3(
    const float* __restrict__ b1, const float* __restrict__ b2,
    const unsigned short* __restrict__ w1b, const unsigned short* __restrict__ w2b,
    const unsigned* __restrict__ desc3, const unsigned* __restrict__ tlist3,
    const float* __restrict__ wp3, const unsigned char* __restrict__ Xp3,
    unsigned char* __restrict__ Op3) {
  __shared__ unsigned char lds[143872];
  // [0,131072)      wbuf[2] x 64KB: ws1 32KB + ws2 32KB (both K-major)
  // [131072,139264) hs: 64t x 128B (64 h bf16), XOR-swizzled
  // [139264,143360) b1S: 1024 f32
  // [143360,143616) tokS ; [143616,143872) w3S
  unsigned char* hs = lds + 131072;
  float* b1S = (float*)(lds + 139264);
  unsigned* tokS = (unsigned*)(lds + 143360);
  float* w3S = (float*)(lds + 143616);

  const unsigned d = desc3[blockIdx.x];
  const unsigned e = d >> 16;
  if (e > 5) return;
  const int lstart = (int)(d & 0xFFFFu) << 6;

  const int tid  = threadIdx.x;
  const int lane = tid & 63;
  const int wv   = tid >> 6;        // 0..7
  const int lr   = lane & 15;
  const int lg   = lane >> 4;
  const int wt   = wv >> 2;         // token half (GEMM1): 32 t
  const int wh   = wv & 3;          // h quarter of chunk (GEMM1): 16 h

  if (tid < TT) { tokS[tid] = tlist3[lstart + tid]; w3S[tid] = wp3[lstart + tid]; }
  *(f32x2*)&b1S[tid * 2] = *(const f32x2*)&b1[e * HID + tid * 2];
  __syncthreads();

  const unsigned char* w1bytes = (const unsigned char*)w1b + (size_t)e * HID * 512;
  const unsigned char* w2bytes = (const unsigned char*)w2b + (size_t)e * CC * 2048;

  // ws1 stage: 32KB K-major; instr i covers kb = wv*... -> per instr 1KB:
  //   kb = (wv*4+i) (K-block of 32 c), h = lane.
  auto STAGE1 = [&](int bufsel, int k2) {
    unsigned char* wb = lds + bufsel * 65536;
    #pragma unroll
    for (int i = 0; i < 4; ++i) {
      unsigned kb = (unsigned)(wv * 4 + i);
      gload16(w1bytes + ((size_t)(k2 * 64 + lane) << 9) + kb * 16,
              wb + kb * 1024 + lane * 16);
    }
  };
  // ws2 stage: 32KB K-major; per instr 1KB: kb = (wv*4+i)>>2, c = ((wv*4+i)&3)*64+lane.
  auto STAGE2 = [&](int bufsel, int k2) {
    unsigned char* wb = lds + bufsel * 65536 + 32768;
    #pragma unroll
    for (int i = 0; i < 4; ++i) {
      unsigned q = (unsigned)(wv * 4 + i);
      unsigned kb = q >> 2, c = (q & 3u) * 64 + lane;
      gload16(w2bytes + (size_t)c * 2048 + (unsigned)(k2 * 128) + kb * 16,
              wb + q * 1024 + lane * 16);
    }
  };

  // prologue: stage chunks 0,1 (16 loads/thread)
  STAGE1(0, 0); STAGE2(0, 0);
  STAGE1(1, 1); STAGE2(1, 1);
  asm volatile("s_waitcnt vmcnt(8)" ::: "memory");   // chunk 0 fully resident
  __builtin_amdgcn_s_barrier();
  asm volatile("" ::: "memory");

  // X fragments in registers (loaded once; compiler tracks their waits)
  bf16x8 bx[2][8];
  #pragma unroll
  for (int fnl = 0; fnl < 2; ++fnl) {
    int t = wt * 32 + fnl * 16 + lr;
    unsigned tk = tokS[t];
    if (tk == SENT) tk = 0u;
    const unsigned char* xr = Xp3 + (size_t)tk * 512;
    #pragma unroll
    for (int ks = 0; ks < 8; ++ks)
      bx[fnl][ks] = *(const bf16x8*)(xr + ks * 64 + lg * 16);
  }

  f32x4 oacc[2][4];   // c = wv*32 + cf*16 + lg*4 + r,  t = fn*16 + lr
  #pragma unroll
  for (int cf = 0; cf < 2; ++cf)
    #pragma unroll
    for (int fn = 0; fn < 4; ++fn) oacc[cf][fn] = (f32x4){0.f, 0.f, 0.f, 0.f};

  const unsigned myh16 = (unsigned)((wh * 16 + lr) * 16);   // ws1 h-offset

  #pragma unroll 1
  for (int k = 0; k < NCH; ++k) {
    unsigned char* wb = lds + (k & 1) * 65536;

    // ---- GEMM1: Hd^T[16h x 32t] per wave over K = C = 256 ----
    f32x4 hacc[2];
    hacc[0] = (f32x4){0.f, 0.f, 0.f, 0.f};
    hacc[1] = (f32x4){0.f, 0.f, 0.f, 0.f};
    __builtin_amdgcn_s_setprio(1);
    #pragma unroll
    for (int ks = 0; ks < 8; ++ks) {
      bf16x8 af = *(const bf16x8*)(wb + (unsigned)((ks * 4 + lg) * 1024) + myh16);
      hacc[0] = __builtin_amdgcn_mfma_f32_16x16x32_bf16(af, bx[0][ks], hacc[0], 0, 0, 0);
      hacc[1] = __builtin_amdgcn_mfma_f32_16x16x32_bf16(af, bx[1][ks], hacc[1], 0, 0, 0);
    }
    __builtin_amdgcn_s_setprio(0);

    // ---- bias + GELU + gate weight -> hs (XOR-swizzled rows) ----
    {
      f32x4 b1v = *(const f32x4*)&b1S[k * 64 + wh * 16 + lg * 4];
      #pragma unroll
      for (int fnl = 0; fnl < 2; ++fnl) {
        int t = wt * 32 + fnl * 16 + lr;
        float msk = w3S[t];
        float gg[4];
        #pragma unroll
        for (int r = 0; r < 4; ++r)
          gg[r] = fast_gelu(hacc[fnl][r] + b1v[r]) * msk;
        u32x2 pk;
        pk[0] = cvt_pk_bf16(gg[0], gg[1]);
        pk[1] = cvt_pk_bf16(gg[2], gg[3]);
        *(u32x2*)(hs + t * 128 +
                  (((unsigned)(wh * 32 + lg * 8)) ^ (((unsigned)(t & 7)) << 4))) = pk;
      }
    }
    asm volatile("s_waitcnt lgkmcnt(0)" ::: "memory");
    __builtin_amdgcn_s_barrier();          // A: hs ready; ws1[k&1] free
    asm volatile("" ::: "memory");
    if (k + 2 < NCH) STAGE1(k & 1, k + 2);   // hides under GEMM2

    // ---- GEMM2: oacc += w2[:,chunk] x Hd^T  (K = 64 h) ----
    __builtin_amdgcn_s_setprio(1);
    #pragma unroll
    for (int ks2 = 0; ks2 < 2; ++ks2) {
      bf16x8 bh[4];
      #pragma unroll
      for (int fn = 0; fn < 4; ++fn) {
        int t = fn * 16 + lr;
        bh[fn] = *(const bf16x8*)(hs + t * 128 +
                  (((unsigned)(ks2 * 64 + lg * 16)) ^ (((unsigned)(t & 7)) << 4)));
      }
      #pragma unroll
      for (int cf = 0; cf < 2; ++cf) {
        bf16x8 am = *(const bf16x8*)(wb + 32768 +
                     (unsigned)((ks2 * 4 + lg) * 4096) +
                     (unsigned)((wv * 32 + cf * 16 + lr) * 16));
        #pragma unroll
        for (int fn = 0; fn < 4; ++fn)
          oacc[cf][fn] =
              __builtin_amdgcn_mfma_f32_16x16x32_bf16(am, bh[fn], oacc[cf][fn], 0, 0, 0);
      }
    }
    __builtin_amdgcn_s_setprio(0);

    if (k < NCH - 1) {
      if (k + 2 < NCH) {
        asm volatile("s_waitcnt vmcnt(4)" ::: "memory");   // chunk k+1 resident
      } else {
        asm volatile("s_waitcnt vmcnt(0)" ::: "memory");
      }
      __builtin_amdgcn_s_barrier();        // B: visible to all; ws2[k&1] free
      asm volatile("" ::: "memory");
      if (k + 2 < NCH) STAGE2(k & 1, k + 2);
    }
  }

  // ---------- epilogue: += w3[t]*b2[e][c]; bf16 Op3 rows ----------
  float wt3[4];
  #pragma unroll
  for (int fn = 0; fn < 4; ++fn) wt3[fn] = w3S[fn * 16 + lr];
  #pragma unroll
  for (int cf = 0; cf < 2; ++cf) {
    f32x4 b2v = *(const f32x4*)&b2[e * CC + wv * 32 + cf * 16 + lg * 4];
    #pragma unroll
    for (int fn = 0; fn < 4; ++fn)
      #pragma unroll
      for (int r = 0; r < 4; ++r)
        oacc[cf][fn][r] = __builtin_fmaf(wt3[fn], b2v[r], oacc[cf][fn][r]);
  }
  #pragma unroll
  for (int fn = 0; fn < 4; ++fn) {
    const int row = lstart + fn * 16 + lr;
    unsigned char* po = Op3 + (size_t)row * 512;
    #pragma unroll
    for (int cf = 0; cf < 2; ++cf) {
      u32x2 pk;
      pk[0] = cvt_pk_bf16(oacc[cf][fn][0], oacc[cf][fn][1]);
      pk[1] = cvt_pk_bf16(oacc[cf][fn][2], oacc[cf][fn][3]);
      *(u32x2*)(po + (wv * 32 + cf * 16 + lg * 4) * 2) = pk;
    }
  }
}

// ---------- unscatter3: sum 3 bf16 rows per token -> out[b][c][n] ----------
__global__ __launch_bounds__(256) void unscatter3_k(
    const unsigned char* __restrict__ Op3, const unsigned* __restrict__ pos3,
    float* __restrict__ out) {
  __shared__ float lo[32 * 261];            // stride 261: conflict-free transpose
  __shared__ unsigned psf[96];
  const int tid = threadIdx.x;
  const int n0g = blockIdx.x * 32;
  const int b = n0g >> 15, n0 = n0g & (NN - 1);

  if (tid < 96) psf[tid] = pos3[(size_t)n0g * 3 + tid];
  __syncthreads();

  #pragma unroll
  for (int j = 0; j < 8; ++j) {
    const int row = j * 4 + (tid >> 6);
    const int c = (tid & 63) * 4;
    float a0 = 0.f, a1 = 0.f, a2 = 0.f, a3 = 0.f;
    #pragma unroll
    for (int s = 0; s < 3; ++s) {
      const unsigned r = psf[row * 3 + s];
      u32x2 v = *(const u32x2*)(Op3 + (size_t)r * 512 + c * 2);
      a0 += __builtin_bit_cast(float, v[0] << 16);
      a1 += __builtin_bit_cast(float, v[0] & 0xFFFF0000u);
      a2 += __builtin_bit_cast(float, v[1] << 16);
      a3 += __builtin_bit_cast(float, v[1] & 0xFFFF0000u);
    }
    lo[row * 261 + c + 0] = a0; lo[row * 261 + c + 1] = a1;
    lo[row * 261 + c + 2] = a2; lo[row * 261 + c + 3] = a3;
  }
  __syncthreads();

  const int noff = tid & 31, cq = tid >> 5;
  float* po = out + (size_t)b * CC * NN + n0 + noff;
  #pragma unroll
  for (int j2 = 0; j2 < 32; ++j2) {
    int c = cq * 32 + j2;
    po[(size_t)c * NN] = lo[noff * 261 + c];
  }
}

// ================================================================
// =============  BUCKET PATH (R6, proven fallback)  ==============
// ================================================================

__global__ __launch_bounds__(256) void gate_k(
    const float* __restrict__ x, const float* __restrict__ attn,
    const float* __restrict__ gate_w, const float* __restrict__ gate_b,
    unsigned* __restrict__ setid, float* __restrict__ wsel,
    unsigned* __restrict__ bhist) {
  __shared__ float gws[EE * CC];
  __shared__ unsigned hist[20];
  const int tid = threadIdx.x;
  const int blk = blockIdx.x;
  for (int i = tid; i < EE * CC; i += 256) gws[i] = gate_w[i];
  if (tid < 20) hist[tid] = 0;
  __syncthreads();

  const unsigned id = blk * 256 + tid;
  const int b = id >> 15, n = id & (NN - 1);
  const float* px = x + (size_t)b * CC * NN + n;
  float g[EE] = {0.f, 0.f, 0.f, 0.f, 0.f, 0.f};
  #pragma unroll 4
  for (int c = 0; c < CC; ++c) {
    float xv = px[(size_t)c * NN];
    #pragma unroll
    for (int e = 0; e < EE; ++e) g[e] = __builtin_fmaf(xv, gws[e * CC + c], g[e]);
  }
  float aw = attn[id];
  float m = -1e30f;
  #pragma unroll
  for (int e = 0; e < EE; ++e) { g[e] = (g[e] + gate_b[e]) * aw; m = fmaxf(m, g[e]); }
  float ex[EE], s = 0.f;
  #pragma unroll
  for (int e = 0; e < EE; ++e) { ex[e] = expf(g[e] - m); s += ex[e]; }
  int i1 = 0; float v1 = g[0];
  #pragma unroll
  for (int e = 1; e < EE; ++e) if (g[e] > v1) { v1 = g[e]; i1 = e; }
  int i2 = -1; float v2 = -3.4e38f;
  #pragma unroll
  for (int e = 0; e < EE; ++e) if (e != i1 && g[e] > v2) { v2 = g[e]; i2 = e; }
  int i3 = -1; float v3 = -3.4e38f;
  #pragma unroll
  for (int e = 0; e < EE; ++e) if (e != i1 && e != i2 && g[e] > v3) { v3 = g[e]; i3 = e; }
  const unsigned msk = (1u << i1) | (1u << i2) | (1u << i3);
  const unsigned bkt = M2B[msk];
  float inv = 1.f / s;
  int slot = 0;
  #pragma unroll
  for (int e = 0; e < EE; ++e)
    if ((msk >> e) & 1u) wsel[(size_t)id * 3 + (slot++)] = ex[e] * inv;
  setid[id] = bkt;
  atomicAdd(&hist[bkt], 1u);
  __syncthreads();
  if (tid < 20) bhist[blk * 20 + tid] = hist[tid];
}

__global__ void prefix_k(const unsigned* __restrict__ bhist, unsigned* __restrict__ bbase,
                         unsigned* __restrict__ desc) {
  __shared__ unsigned tot[20];
  __shared__ unsigned bb[21];
  __shared__ unsigned tcum[21];
  const int tid = threadIdx.x;
  if (tid < 20) {
    unsigned run = 0;
    for (int blk = 0; blk < 256; ++blk) {
      unsigned v = bhist[blk * 20 + tid];
      bbase[blk * 20 + tid] = run;
      run += v;
    }
    tot[tid] = run;
  }
  __syncthreads();
  if (tid == 0) {
    unsigned base = 0, tc = 0;
    for (int b = 0; b < 20; ++b) {
      bb[b] = base; tcum[b] = tc;
      unsigned tl = (tot[b] + 63) >> 6;
      tc += tl; base += tl << 6;
    }
    bb[20] = base; tcum[20] = tc;
  }
  __syncthreads();
  if (tid < 20) {
    unsigned b0 = bb[tid];
    for (int blk = 0; blk < 256; ++blk) bbase[blk * 20 + tid] += b0;
  }
  __syncthreads();
  const unsigned nt = tcum[20];
  for (int i = tid; i < NTILE_MAX; i += 256) {
    unsigned d;
    if ((unsigned)i < nt) {
      int b = 0;
      while (!((unsigned)i >= tcum[b] && (unsigned)i < tcum[b + 1])) ++b;
      d = ((unsigned)b << 16) | ((bb[b] >> 6) + ((unsigned)i - tcum[b]));
    } else {
      d = 0x003F0000u;
    }
    desc[i] = d;
  }
}

__global__ __launch_bounds__(256) void scatter_k(
    const unsigned* __restrict__ setid, const unsigned* __restrict__ bbase,
    const float* __restrict__ wsel,
    unsigned* __restrict__ pos, float* __restrict__ wp) {
  __shared__ unsigned wcnt[4][20];
  const int tid = threadIdx.x, lane = tid & 63, w = tid >> 6;
  const int blk = blockIdx.x;
  const unsigned id = blk * 256 + tid;
  const unsigned sid = setid[id];
  unsigned long long myb = 0;
  #pragma unroll
  for (int b = 0; b < 20; ++b) {
    unsigned long long bl = __ballot(sid == (unsigned)b);
    if (lane == 0) wcnt[w][b] = (unsigned)__builtin_popcountll(bl);
    if ((unsigned)b == sid) myb = bl;
  }
  __syncthreads();
  unsigned rank = 0;
  #pragma unroll
  for (int w2 = 0; w2 < 4; ++w2) if (w2 < w) rank += wcnt[w2][sid];
  rank += (unsigned)__builtin_popcountll(myb & ((1ull << lane) - 1ull));
  const unsigned p = bbase[blk * 20 + sid] + rank;
  pos[id] = p;
  #pragma unroll
  for (int s = 0; s < 3; ++s) wp[(size_t)p * 3 + s] = wsel[(size_t)id * 3 + s];
}

__global__ __launch_bounds__(256) void xpack_k(
    const float* __restrict__ x, const unsigned* __restrict__ pos,
    unsigned char* __restrict__ Xp) {
  __shared__ unsigned char lx[TT * 512];
  __shared__ unsigned posS[TT];
  const int tid = threadIdx.x, lane = tid & 63, wv = tid >> 6;
  const int n0g = blockIdx.x * TT;
  const int b = n0g >> 15, n0 = n0g & (NN - 1);

  if (tid < TT) posS[tid] = pos[n0g + tid];

  const float* px = x + (size_t)b * CC * NN + n0 + lane;
  #pragma unroll 1
  for (int c8 = 0; c8 < 8; ++c8) {
    float xv[8];
    #pragma unroll
    for (int j = 0; j < 8; ++j)
      xv[j] = px[(size_t)(wv * 64 + c8 * 8 + j) * NN];
    u32x4 pk;
    #pragma unroll
    for (int q = 0; q < 4; ++q) pk[q] = cvt_pk_bf16(xv[2 * q], xv[2 * q + 1]);
    *(u32x4*)(lx + lane * 512 + (wv * 64 + c8 * 8) * 2) = pk;
  }
  __syncthreads();

  #pragma unroll 1
  for (int r = 0; r < 16; ++r) {
    const int t = wv * 16 + r;
    const unsigned p = posS[t];
    u32x2 v = *(const u32x2*)(lx + t * 512 + lane * 8);
    *(u32x2*)(Xp + (size_t)p * 512 + (((unsigned)(lane * 8)) ^ (((unsigned)(p & 31)) << 4))) = v;
  }
}

__global__ __launch_bounds__(256, 2) void moe_main(
    const float* __restrict__ b1, const float* __restrict__ b2,
    const unsigned short* __restrict__ w1b, const unsigned short* __restrict__ w2b,
    const unsigned* __restrict__ desc, const float* __restrict__ wp,
    const unsigned char* __restrict__ Xp, float* __restrict__ Op) {
  __shared__ unsigned char xs[TT * CC * 2];
  __shared__ unsigned char hs[TT * 256 * 2];
  __shared__ float w3S[3 * TT];

  const unsigned d = desc[blockIdx.x];
  const unsigned bkt = d >> 16;
  if (bkt > 19) return;
  const int lstart = (int)(d & 0xFFFFu) << 6;

  const int tid  = threadIdx.x;
  const int lane = tid & 63;
  const int wv   = tid >> 6;
  const int lr   = lane & 15;
  const int lg   = lane >> 4;

  if (tid < 3 * TT) {
    int t = tid & 63, s = tid >> 6;
    w3S[s * 64 + t] = wp[(size_t)(lstart + t) * 3 + s];
  }

  {
    const unsigned char* src = Xp + (size_t)lstart * 512;
    #pragma unroll
    for (int it = 0; it < 8; ++it) {
      u32x4 v = *(const u32x4*)(src + it * 4096 + tid * 16);
      *(u32x4*)(xs + it * 4096 + tid * 16) = v;
    }
  }
  __syncthreads();

  f32x4 oacc[4][4];
  #pragma unroll
  for (int fm = 0; fm < 4; ++fm)
    #pragma unroll
    for (int fn = 0; fn < 4; ++fn) oacc[fm][fn] = (f32x4){0.f, 0.f, 0.f, 0.f};

  unsigned trowA[4], tswA[4];
  #pragma unroll
  for (int fn = 0; fn < 4; ++fn) {
    int t = fn * 16 + lr;
    trowA[fn] = (unsigned)t * 512u;
    tswA[fn]  = ((unsigned)(t & 31)) << 4;
  }

  #pragma unroll 1
  for (int xe = 0; xe < 3; ++xe) {
    const int e = CMB[bkt][xe];
    #pragma unroll 1
    for (int sc = 0; sc < 4; ++sc) {
      f32x4 hacc[4][4];
      #pragma unroll
      for (int fm = 0; fm < 4; ++fm)
        #pragma unroll
        for (int fn = 0; fn < 4; ++fn) hacc[fm][fn] = (f32x4){0.f, 0.f, 0.f, 0.f};
      const unsigned short* w1p =
          w1b + ((size_t)(e * HID + sc * 256 + wv * 64 + lr)) * CC + lg * 8;
      #pragma unroll
      for (int ks = 0; ks < 8; ++ks) {
        bf16x8 af[4], bxv[4];
        #pragma unroll
        for (int fm = 0; fm < 4; ++fm)
          af[fm] = *(const bf16x8*)(w1p + fm * 16 * CC + ks * 32);
        #pragma unroll
        for (int fn = 0; fn < 4; ++fn)
          bxv[fn] = *(const bf16x8*)(xs + trowA[fn] +
                                    (((unsigned)(ks * 64 + lg * 16)) ^ tswA[fn]));
        #pragma unroll
        for (int fn = 0; fn < 4; ++fn)
          #pragma unroll
          for (int fm = 0; fm < 4; ++fm)
            hacc[fm][fn] =
                __builtin_amdgcn_mfma_f32_16x16x32_bf16(af[fm], bxv[fn], hacc[fm][fn], 0, 0, 0);
      }
      {
        f32x4 b1v[4];
        #pragma unroll
        for (int fm = 0; fm < 4; ++fm)
          b1v[fm] = *(const f32x4*)&b1[e * HID + sc * 256 + wv * 64 + fm * 16 + lg * 4];
        #pragma unroll
        for (int fn = 0; fn < 4; ++fn) {
          float msk = w3S[xe * 64 + fn * 16 + lr];
          #pragma unroll
          for (int fm = 0; fm < 4; ++fm) {
            float gg[4];
            #pragma unroll
            for (int r = 0; r < 4; ++r)
              gg[r] = fast_gelu(hacc[fm][fn][r] + b1v[fm][r]) * msk;
            u32x2 pk;
            pk[0] = cvt_pk_bf16(gg[0], gg[1]);
            pk[1] = cvt_pk_bf16(gg[2], gg[3]);
            unsigned byteo = trowA[fn] +
                (((unsigned)((wv * 64 + fm * 16 + lg * 4) * 2)) ^ tswA[fn]);
            *(u32x2*)(hs + byteo) = pk;
          }
        }
      }
      __syncthreads();
      const unsigned short* w2p =
          w2b + ((size_t)(e * CC + wv * 64 + lr)) * HID + sc * 256 + lg * 8;
      #pragma unroll
      for (int ks = 0; ks < 8; ++ks) {
        bf16x8 am[4], bh[4];
        #pragma unroll
        for (int fm = 0; fm < 4; ++fm)
          am[fm] = *(const bf16x8*)(w2p + fm * 16 * HID + ks * 32);
        #pragma unroll
        for (int fn = 0; fn < 4; ++fn)
          bh[fn] = *(const bf16x8*)(hs + trowA[fn] +
                                    (((unsigned)(ks * 64 + lg * 16)) ^ tswA[fn]));
        #pragma unroll
        for (int fn = 0; fn < 4; ++fn)
          #pragma unroll
          for (int fm = 0; fm < 4; ++fm)
            oacc[fm][fn] =
                __builtin_amdgcn_mfma_f32_16x16x32_bf16(am[fm], bh[fn], oacc[fm][fn], 0, 0, 0);
      }
      __syncthreads();
    }
  }

  #pragma unroll
  for (int xe = 0; xe < 3; ++xe) {
    const int e = CMB[bkt][xe];
    float msk[4];
    #pragma unroll
    for (int fn = 0; fn < 4; ++fn) msk[fn] = w3S[xe * 64 + fn * 16 + lr];
    #pragma unroll
    for (int fm = 0; fm < 4; ++fm) {
      f32x4 b2v = *(const f32x4*)&b2[e * CC + wv * 64 + fm * 16 + lg * 4];
      #pragma unroll
      for (int fn = 0; fn < 4; ++fn)
        #pragma unroll
        for (int r = 0; r < 4; ++r)
          oacc[fm][fn][r] = __builtin_fmaf(msk[fn], b2v[r], oacc[fm][fn][r]);
    }
  }
  #pragma unroll
  for (int fn = 0; fn < 4; ++fn) {
    float* po = Op + (size_t)(lstart + fn * 16 + lr) * CC;
    #pragma unroll
    for (int fm = 0; fm < 4; ++fm)
      *(f32x4*)(po + wv * 64 + fm * 16 + lg * 4) = oacc[fm][fn];
  }
}

__global__ __launch_bounds__(256) void unscatter_k(
    const float* __restrict__ Op, const unsigned* __restrict__ pos,
    float* __restrict__ out) {
  __shared__ float lo[32 * 261];
  __shared__ unsigned posS[32];
  const int tid = threadIdx.x;
  const int n0g = blockIdx.x * 32;
  const int b = n0g >> 15, n0 = n0g & (NN - 1);

  if (tid < 32) posS[tid] = pos[n0g + tid];
  __syncthreads();

  #pragma unroll
  for (int j = 0; j < 8; ++j) {
    int fidx = j * 1024 + tid * 4;
    int row = fidx >> 8, c = fidx & 255;
    f32x4 v = *(const f32x4*)(Op + (size_t)posS[row] * CC + c);
    #pragma unroll
    for (int i = 0; i < 4; ++i) lo[row * 261 + c + i] = v[i];
  }
  __syncthreads();

  const int noff = tid & 31, cq = tid >> 5;
  float* po = out + (size_t)b * CC * NN + n0 + noff;
  #pragma unroll
  for (int j2 = 0; j2 < 32; ++j2) {
    int c = cq * 32 + j2;
    po[(size_t)c * NN] = lo[noff * 261 + c];
  }
}

// ================================================================

extern "C" void kernel_launch(void* const* d_in, const int* in_sizes, int n_in,
                              void* d_out, int out_size, void* d_ws, size_t ws_size,
                              hipStream_t stream) {
  const float* x      = (const float*)d_in[0];
  const float* attn   = (const float*)d_in[1];
  const float* gate_w = (const float*)d_in[2];
  const float* gate_b = (const float*)d_in[3];
  const float* w1     = (const float*)d_in[4];
  const float* b1     = (const float*)d_in[5];
  const float* w2     = (const float*)d_in[6];
  const float* b2     = (const float*)d_in[7];
  float* out = (float*)d_out;

  unsigned char* ws = (unsigned char*)d_ws;
  // shared head
  unsigned short* w1b  = (unsigned short*)(ws);             // 3,145,728
  unsigned short* w2b  = (unsigned short*)(ws + 3145728);   // -> 6,291,456
  unsigned*       setid= (unsigned*)(ws + 6291456);         // -> 6,553,600
  float*          wsel = (float*)(ws + 6553600);            // -> 7,340,032
  // bucket-path tail (aliases expert-major tail; exclusive)
  unsigned*       bhist= (unsigned*)(ws + 7340032);         // 20,480
  unsigned*       bbase= (unsigned*)(ws + 7360512);         // 20,480
  unsigned*       desc = (unsigned*)(ws + 7381120);         // 4,224
  unsigned*       pos  = (unsigned*)(ws + 7385344);         // 262,144
  float*          wp   = (float*)(ws + 7647488);            // 801,792
  unsigned char*  Xp   = (unsigned char*)(ws + 8449280);    // 34,209,792
  float*          Op   = (float*)(ws + 42659072);           // 68,419,584
  const size_t need_bucket = 111078656;
  // expert-major tail (starts after wsel)
  unsigned*       ehist = (unsigned*)(ws + 7360512);        // 24,576
  unsigned*       ebase = (unsigned*)(ws + 7385088);        // 24,576
  unsigned*       desc3 = (unsigned*)(ws + 7409664);        // 26,624
  unsigned*       tlist3= (unsigned*)(ws + 7436288);        // 787,968
  float*          wp3   = (float*)(ws + 8224256);           // 787,968
  unsigned*       pos3  = (unsigned*)(ws + 9012224);        // 786,432
  unsigned char*  Xp3   = (unsigned char*)(ws + 9798656);   // 33,554,432
  unsigned char*  Op3   = (unsigned char*)(ws + 43353088);  // 100,859,904
  const size_t need3 = 144212992;

  wconv<<<(EE * HID * CC) / 256, 256, 0, stream>>>(w1, w2, w1b, w2b);
  if (ws_size >= need3) {
    gatepack_k<<<NTOK / TT, 256, 0, stream>>>(x, attn, gate_w, gate_b, setid, wsel, ehist, Xp3);
    prefix3_k<<<1, 256, 0, stream>>>(ehist, ebase, desc3, tlist3, wp3);
    scatter3_k<<<NTOK / 64, 64, 0, stream>>>(setid, ebase, wsel, tlist3, wp3, pos3);
    moe_main3<<<NT3MAX, 512, 0, stream>>>(b1, b2, w1b, w2b, desc3, tlist3, wp3, Xp3, Op3);
    unscatter3_k<<<NTOK / 32, 256, 0, stream>>>(Op3, pos3, out);
  } else {
    gate_k<<<NTOK / 256, 256, 0, stream>>>(x, attn, gate_w, gate_b, setid, wsel, bhist);
    prefix_k<<<1, 256, 0, stream>>>(bhist, bbase, desc);
    scatter_k<<<NTOK / 256, 256, 0, stream>>>(setid, bbase, wsel, pos, wp);
    xpack_k<<<NTOK / TT, 256, 0, stream>>>(x, pos, Xp);
    moe_main<<<NTILE_MAX, 256, 0, stream>>>(b1, b2, w1b, w2b, desc, wp, Xp, Op);
    unscatter_k<<<NTOK / 32, 256, 0, stream>>>(Op, pos, out);
  }
}

// Round 16
// 499.736 us; speedup vs baseline: 1.1530x; 1.1530x over previous
//
#include <hip/hip_runtime.h>
#include <hip/hip_bf16.h>
#include <math.h>

// Problem constants
#define NN 32768          // Dd*Hh*Ww tokens per batch
#define CC 256
#define EE 6
#define HID 1024
#define TT 64             // tokens per tile
#define NTOK 65536        // B * NN
#define NTILE_MAX 1044    // bucket path tiles
#define NT3MAX 3078       // expert-major 64-row tiles
#define NCH 16            // h-chunks per tile (64 h each)
#define SENT 0xFFFFFFFFu

typedef __attribute__((ext_vector_type(8))) short bf16x8;
typedef __attribute__((ext_vector_type(4))) float f32x4;
typedef __attribute__((ext_vector_type(2))) float f32x2;
typedef __attribute__((ext_vector_type(4))) unsigned int u32x4;
typedef __attribute__((ext_vector_type(2))) unsigned int u32x2;

// lexicographic 3-subsets of {0..5}
__device__ const int CMB[20][3] = {
  {0,1,2},{0,1,3},{0,1,4},{0,1,5},{0,2,3},{0,2,4},{0,2,5},{0,3,4},{0,3,5},{0,4,5},
  {1,2,3},{1,2,4},{1,2,5},{1,3,4},{1,3,5},{1,4,5},{2,3,4},{2,3,5},{2,4,5},{3,4,5}};
// expert-bitmask -> bucket id (255 = invalid)
__device__ const unsigned char M2B[64] = {
  255,255,255,255,255,255,255,  0,
  255,255,255,  1,255,  4, 10,255,
  255,255,255,  2,255,  5, 11,255,
  255,  7, 13,255, 16,255,255,255,
  255,255,255,  3,255,  6, 12,255,
  255,  8, 14,255, 17,255,255,255,
  255,  9, 15,255, 18,255,255,255,
   19,255,255,255,255,255,255,255};

__device__ __forceinline__ unsigned short f32_bf16(float f) {
  unsigned u = __builtin_bit_cast(unsigned, f);
  u += 0x7FFFu + ((u >> 16) & 1u);          // RNE
  return (unsigned short)(u >> 16);
}

__device__ __forceinline__ unsigned cvt_pk_bf16(float lo, float hi) {
  unsigned r;
  asm("v_cvt_pk_bf16_f32 %0, %1, %2" : "=v"(r) : "v"(lo), "v"(hi));
  return r;
}

// tanh-form GELU via sigmoid identity; max abs dev from erf-GELU ~1e-3.
__device__ __forceinline__ float fast_gelu(float v) {
  float s = v * v;
  float a = v * -2.3021181819f;
  float m = a * 0.044715f;
  float nu = __builtin_fmaf(m, s, a);
  float z = __builtin_amdgcn_exp2f(nu);
  return v * __builtin_amdgcn_rcpf(1.0f + z);
}

// async global->LDS, 16B per lane; LDS dest is wave-linear (base + lane*16)
typedef __attribute__((address_space(3))) void lds_void;
typedef __attribute__((address_space(1))) const void glb_void;
__device__ __forceinline__ void gload16(const void* g, void* l) {
  __builtin_amdgcn_global_load_lds((glb_void*)g, (lds_void*)l, 16, 0, 0);
}

// ---------- one-time f32 -> bf16 weight conversion ----------
__global__ void wconv(const float* __restrict__ w1, const float* __restrict__ w2,
                      unsigned short* __restrict__ w1b, unsigned short* __restrict__ w2b) {
  int i = blockIdx.x * 256 + threadIdx.x;
  w1b[i] = f32_bf16(w1[i]);
  w2b[i] = f32_bf16(w2[i]);
}

// ================================================================
// ====================  EXPERT-MAJOR PATH  =======================
// ================================================================

// gating + X packing fused
__global__ __launch_bounds__(256) void gatepack_k(
    const float* __restrict__ x, const float* __restrict__ attn,
    const float* __restrict__ gate_w, const float* __restrict__ gate_b,
    unsigned* __restrict__ setid, float* __restrict__ wsel,
    unsigned* __restrict__ ehist, unsigned char* __restrict__ Xp3) {
  __shared__ float gws[EE * CC];            // 6 KB
  __shared__ unsigned char lx[TT * 512];    // 32 KB linear [t][c*2]
  __shared__ float gred[256 * EE];          // 6 KB
  __shared__ unsigned hist6[EE];

  const int tid = threadIdx.x, lane = tid & 63, wv = tid >> 6;
  const int n0g = blockIdx.x * TT;
  const int bI = n0g >> 15, n0 = n0g & (NN - 1);

  for (int i = tid; i < EE * CC; i += 256) gws[i] = gate_w[i];
  if (tid < EE) hist6[tid] = 0;
  __syncthreads();

  {
    float gp[EE] = {0.f, 0.f, 0.f, 0.f, 0.f, 0.f};
    const size_t xbase = ((size_t)bI * CC + wv * 64) * NN + n0 + lane;
    #pragma unroll 1
    for (int c8 = 0; c8 < 8; ++c8) {
      float xv[8];
      #pragma unroll
      for (int j = 0; j < 8; ++j)
        xv[j] = x[xbase + (size_t)(c8 * 8 + j) * NN];   // coalesced over lanes
      #pragma unroll
      for (int j = 0; j < 8; ++j) {
        int c = wv * 64 + c8 * 8 + j;
        #pragma unroll
        for (int e = 0; e < EE; ++e) gp[e] = __builtin_fmaf(xv[j], gws[e * CC + c], gp[e]);
      }
      u32x4 pk;
      #pragma unroll
      for (int q = 0; q < 4; ++q) pk[q] = cvt_pk_bf16(xv[2 * q], xv[2 * q + 1]);
      *(u32x4*)(lx + lane * 512 + (wv * 64 + c8 * 8) * 2) = pk;
    }
    #pragma unroll
    for (int e = 0; e < EE; ++e) gred[(wv * 64 + lane) * EE + e] = gp[e];
  }
  __syncthreads();

  if (tid < 64) {
    float g[EE];
    #pragma unroll
    for (int e = 0; e < EE; ++e)
      g[e] = gred[(0 * 64 + tid) * EE + e] + gred[(1 * 64 + tid) * EE + e] +
             gred[(2 * 64 + tid) * EE + e] + gred[(3 * 64 + tid) * EE + e];
    float aw = attn[n0g + tid];
    float m = -1e30f;
    #pragma unroll
    for (int e = 0; e < EE; ++e) { g[e] = (g[e] + gate_b[e]) * aw; m = fmaxf(m, g[e]); }
    float ex[EE], s = 0.f;
    #pragma unroll
    for (int e = 0; e < EE; ++e) { ex[e] = expf(g[e] - m); s += ex[e]; }
    int i1 = 0; float v1 = g[0];
    #pragma unroll
    for (int e = 1; e < EE; ++e) if (g[e] > v1) { v1 = g[e]; i1 = e; }
    int i2 = -1; float v2 = -3.4e38f;
    #pragma unroll
    for (int e = 0; e < EE; ++e) if (e != i1 && g[e] > v2) { v2 = g[e]; i2 = e; }
    int i3 = -1; float v3 = -3.4e38f;
    #pragma unroll
    for (int e = 0; e < EE; ++e) if (e != i1 && e != i2 && g[e] > v3) { v3 = g[e]; i3 = e; }
    const unsigned msk = (1u << i1) | (1u << i2) | (1u << i3);
    float inv = 1.f / s;
    int slot = 0;
    #pragma unroll
    for (int e = 0; e < EE; ++e)
      if ((msk >> e) & 1u) wsel[(size_t)(n0g + tid) * 3 + (slot++)] = ex[e] * inv;
    setid[n0g + tid] = (unsigned)M2B[msk];
    atomicAdd(&hist6[i1], 1u); atomicAdd(&hist6[i2], 1u); atomicAdd(&hist6[i3], 1u);
  }
  __syncthreads();

  #pragma unroll 1
  for (int r = 0; r < 16; ++r) {
    const int t = wv * 16 + r;
    u32x2 v = *(const u32x2*)(lx + t * 512 + lane * 8);
    *(u32x2*)(Xp3 + (size_t)(n0g + t) * 512 + lane * 8) = v;   // 512B/row coalesced
  }
  if (tid < EE) ehist[tid * 1024 + blockIdx.x] = hist6[tid];
}

// ---------- prefix: per-expert bases, 64-row tile descriptors ----------
// desc encoding: [e:31..16][g:15..0]  (g = 64-row group index)
__global__ __launch_bounds__(256) void prefix3_k(
    const unsigned* __restrict__ ehist, unsigned* __restrict__ ebase,
    unsigned* __restrict__ desc3, unsigned* __restrict__ tlist3,
    float* __restrict__ wp3) {
  __shared__ unsigned sc[256];
  __shared__ unsigned tot[EE], bb[EE + 1], tcum[EE + 1];
  const int tid = threadIdx.x;
  #pragma unroll 1
  for (int e = 0; e < EE; ++e) {
    unsigned v[4]; unsigned s = 0;
    #pragma unroll
    for (int k = 0; k < 4; ++k) { v[k] = ehist[e * 1024 + tid * 4 + k]; s += v[k]; }
    sc[tid] = s; __syncthreads();
    for (int off = 1; off < 256; off <<= 1) {
      unsigned tv = (tid >= off) ? sc[tid - off] : 0u; __syncthreads();
      sc[tid] += tv; __syncthreads();
    }
    unsigned excl = sc[tid] - s;
    if (tid == 255) tot[e] = sc[255];
    unsigned run = excl;
    #pragma unroll
    for (int k = 0; k < 4; ++k) { ebase[e * 1024 + tid * 4 + k] = run; run += v[k]; }
    __syncthreads();
  }
  if (tid == 0) {
    unsigned base = 0, tc = 0;
    for (int e = 0; e < EE; ++e) {
      bb[e] = base; tcum[e] = tc;
      unsigned tl = (tot[e] + 63) >> 6;
      tc += tl; base += tl << 6;
    }
    bb[EE] = base; tcum[EE] = tc;
  }
  __syncthreads();
  #pragma unroll 1
  for (int e = 0; e < EE; ++e) {
    unsigned b0 = bb[e];
    #pragma unroll
    for (int k = 0; k < 4; ++k) ebase[e * 1024 + tid * 4 + k] += b0;
  }
  if (tid < EE) {
    for (unsigned i = bb[tid] + tot[tid]; i < bb[tid + 1]; ++i) {
      tlist3[i] = SENT; wp3[i] = 0.f;
    }
  }
  __syncthreads();
  const unsigned nt = tcum[EE];
  for (int i = tid; i < NT3MAX; i += 256) {
    unsigned d;
    if ((unsigned)i < nt) {
      int e = 0;
      while (!((unsigned)i >= tcum[e] && (unsigned)i < tcum[e + 1])) ++e;
      d = ((unsigned)e << 16) | ((bb[e] >> 6) + ((unsigned)i - tcum[e]));
    } else d = 0x003F0000u;
    desc3[i] = d;
  }
}

// ---------- scatter3: token -> 3 expert-list entries (deterministic) ----------
__global__ __launch_bounds__(64) void scatter3_k(
    const unsigned* __restrict__ setid, const unsigned* __restrict__ ebase,
    const float* __restrict__ wsel,
    unsigned* __restrict__ tlist3, float* __restrict__ wp3, unsigned* __restrict__ pos3) {
  const int tid = threadIdx.x;
  const int blk = blockIdx.x;
  const unsigned id = blk * 64 + tid;
  const unsigned bkt = setid[id];
  const unsigned m6 =
      (1u << CMB[bkt][0]) | (1u << CMB[bkt][1]) | (1u << CMB[bkt][2]);
  const unsigned long long below = (1ull << tid) - 1ull;
  int s = 0;
  #pragma unroll
  for (int e = 0; e < EE; ++e) {
    unsigned long long bl = __ballot((m6 >> e) & 1u);
    if ((m6 >> e) & 1u) {
      unsigned rank = (unsigned)__builtin_popcountll(bl & below);
      unsigned p = ebase[e * 1024 + blk] + rank;
      tlist3[p] = id;
      wp3[p] = wsel[(size_t)id * 3 + s];
      pos3[(size_t)id * 3 + s] = p;
      s++;
    }
  }
}

// ---------- main3: async-staged weight pipeline (T3+T4+T5) ----------
// 64-token expert-major tile, 512 thr / 8 waves, 1 block/CU.
// 16 h-chunks of 64 h: weights (w1 32KB + w2 32KB) async-staged via
// global_load_lds into double-buffered LDS (pre-swizzled global source,
// linear LDS dest); counted vmcnt(8) keeps next chunk's loads in flight
// across raw barriers. X fragments live in registers (loaded once).
__global__ __launch_bounds__(512, 2) void moe_main3(
    const float* __restrict__ b1, const float* __restrict__ b2,
    const unsigned short* __restrict__ w1b, const unsigned short* __restrict__ w2b,
    const unsigned* __restrict__ desc3, const unsigned* __restrict__ tlist3,
    const float* __restrict__ wp3, const unsigned char* __restrict__ Xp3,
    unsigned char* __restrict__ Op3) {
  __shared__ unsigned char lds[143872];
  // [0,131072)      wbuf[2]: per buffer ws1 32KB (rows h: 512B) + ws2 32KB (rows c: 128B)
  // [131072,139264) hs: 64t x 128B (64 h bf16), swizzled
  // [139264,143360) b1S: 1024 f32
  // [143360,143616) tokS
  // [143616,143872) w3S
  unsigned char* hs = lds + 131072;
  float* b1S = (float*)(lds + 139264);
  unsigned* tokS = (unsigned*)(lds + 143360);
  float* w3S = (float*)(lds + 143616);

  const unsigned d = desc3[blockIdx.x];
  const unsigned e = d >> 16;
  if (e > 5) return;
  const int lstart = (int)(d & 0xFFFFu) << 6;

  const int tid  = threadIdx.x;
  const int lane = tid & 63;
  const int wv   = tid >> 6;        // 0..7
  const int lr   = lane & 15;
  const int lg   = lane >> 4;
  const int wt   = wv >> 2;         // token half (GEMM1)
  const int wh   = wv & 3;          // h fragment (GEMM1)

  if (tid < TT) { tokS[tid] = tlist3[lstart + tid]; w3S[tid] = wp3[lstart + tid]; }
  *(f32x2*)&b1S[tid * 2] = *(const f32x2*)&b1[e * HID + tid * 2];
  __syncthreads();

  const unsigned char* w1bytes = (const unsigned char*)w1b + (size_t)e * HID * 512;
  const unsigned char* w2bytes = (const unsigned char*)w2b + (size_t)e * CC * 2048;

  // per-wave stage of one 64-h chunk: 8 x global_load_lds(16B)
  auto STAGE = [&](int bufsel, int k2) {
    unsigned char* wb = lds + bufsel * 65536;
    #pragma unroll
    for (int i = 0; i < 4; ++i) {
      unsigned slot = (unsigned)(wv * 4096 + i * 1024 + lane * 16);
      unsigned h = slot >> 9;
      unsigned off = (slot & 511u) ^ ((h & 7u) << 4);
      gload16(w1bytes + ((size_t)(k2 * 64 + h) << 9) + off, wb + slot);
    }
    #pragma unroll
    for (int i = 0; i < 4; ++i) {
      unsigned slot = (unsigned)(wv * 4096 + i * 1024 + lane * 16);
      unsigned c = slot >> 7;
      unsigned off = (slot & 127u) ^ ((c & 7u) << 4);
      gload16(w2bytes + (size_t)c * 2048 + (unsigned)(k2 * 128) + off,
              wb + 32768 + slot);
    }
  };

  // prologue: stage chunks 0,1; load X fragments into registers
  STAGE(0, 0);
  STAGE(1, 1);
  asm volatile("" ::: "memory");

  bf16x8 bx[2][8];
  #pragma unroll
  for (int fnl = 0; fnl < 2; ++fnl) {
    int t = wt * 32 + fnl * 16 + lr;
    unsigned tk = tokS[t];
    if (tk == SENT) tk = 0u;
    const unsigned char* xr = Xp3 + (size_t)tk * 512;
    #pragma unroll
    for (int ks = 0; ks < 8; ++ks)
      bx[fnl][ks] = *(const bf16x8*)(xr + ks * 64 + lg * 16);
  }
  asm volatile("s_waitcnt vmcnt(24)" ::: "memory");   // chunk0 staged (16 stage1+bx... bx tracked by compiler)
  __builtin_amdgcn_s_barrier();
  asm volatile("" ::: "memory");

  f32x4 oacc[2][4];   // c = wv*32 + cf*16 + lg*4 + r,  t = fn*16 + lr
  #pragma unroll
  for (int cf = 0; cf < 2; ++cf)
    #pragma unroll
    for (int fn = 0; fn < 4; ++fn) oacc[cf][fn] = (f32x4){0.f, 0.f, 0.f, 0.f};

  const unsigned myrow = (unsigned)(wh * 16 + lr);            // ws1 row for GEMM1
  const unsigned rsw   = (myrow & 7u) << 4;

  #pragma unroll 1
  for (int k = 0; k < NCH; ++k) {
    unsigned char* wb = lds + (k & 1) * 65536;

    // ---- GEMM1: Hd^T[16h x 32t] per wave over K=C=256 ----
    f32x4 hacc[2];
    hacc[0] = (f32x4){0.f, 0.f, 0.f, 0.f};
    hacc[1] = (f32x4){0.f, 0.f, 0.f, 0.f};
    __builtin_amdgcn_s_setprio(1);
    #pragma unroll
    for (int ks = 0; ks < 8; ++ks) {
      bf16x8 af = *(const bf16x8*)(wb + myrow * 512 +
                                   (((unsigned)(ks * 64 + lg * 16)) ^ rsw));
      hacc[0] = __builtin_amdgcn_mfma_f32_16x16x32_bf16(af, bx[0][ks], hacc[0], 0, 0, 0);
      hacc[1] = __builtin_amdgcn_mfma_f32_16x16x32_bf16(af, bx[1][ks], hacc[1], 0, 0, 0);
    }
    __builtin_amdgcn_s_setprio(0);

    // ---- bias + GELU + gate weight -> hs (swizzled) ----
    {
      f32x4 b1v = *(const f32x4*)&b1S[k * 64 + wh * 16 + lg * 4];
      #pragma unroll
      for (int fnl = 0; fnl < 2; ++fnl) {
        int t = wt * 32 + fnl * 16 + lr;
        float msk = w3S[t];
        float gg[4];
        #pragma unroll
        for (int r = 0; r < 4; ++r)
          gg[r] = fast_gelu(hacc[fnl][r] + b1v[r]) * msk;
        u32x2 pk;
        pk[0] = cvt_pk_bf16(gg[0], gg[1]);
        pk[1] = cvt_pk_bf16(gg[2], gg[3]);
        *(u32x2*)(hs + t * 128 +
                  (((unsigned)(wh * 32 + lg * 8)) ^ (((unsigned)(t & 7)) << 4))) = pk;
      }
    }
    asm volatile("s_waitcnt lgkmcnt(0)" ::: "memory");
    __builtin_amdgcn_s_barrier();
    asm volatile("" ::: "memory");

    // ---- GEMM2: oacc += w2[:,chunk] x Hd^T  (K = 64 h) ----
    __builtin_amdgcn_s_setprio(1);
    #pragma unroll
    for (int ks2 = 0; ks2 < 2; ++ks2) {
      bf16x8 bh[4];
      #pragma unroll
      for (int fn = 0; fn < 4; ++fn) {
        int t = fn * 16 + lr;
        bh[fn] = *(const bf16x8*)(hs + t * 128 +
                  (((unsigned)(ks2 * 64 + lg * 16)) ^ (((unsigned)(t & 7)) << 4)));
      }
      #pragma unroll
      for (int cf = 0; cf < 2; ++cf) {
        unsigned c = (unsigned)(wv * 32 + cf * 16 + lr);
        bf16x8 am = *(const bf16x8*)(wb + 32768 + c * 128 +
                    (((unsigned)(ks2 * 64 + lg * 16)) ^ ((c & 7u) << 4)));
        #pragma unroll
        for (int fn = 0; fn < 4; ++fn)
          oacc[cf][fn] =
              __builtin_amdgcn_mfma_f32_16x16x32_bf16(am, bh[fn], oacc[cf][fn], 0, 0, 0);
      }
    }
    __builtin_amdgcn_s_setprio(0);

    if (k < NCH - 1) {
      asm volatile("" ::: "memory");
      __builtin_amdgcn_s_barrier();          // all waves done with wb + hs
      asm volatile("" ::: "memory");
      if (k + 2 < NCH) {
        STAGE(k & 1, k + 2);
        asm volatile("s_waitcnt vmcnt(8)" ::: "memory");   // chunk k+1 resident
      } else {
        asm volatile("s_waitcnt vmcnt(0)" ::: "memory");   // last chunk resident
      }
      __builtin_amdgcn_s_barrier();
      asm volatile("" ::: "memory");
    }
  }

  // ---------- epilogue: += w3[t]*b2[e][c]; bf16 Op3 rows ----------
  float wt3[4];
  #pragma unroll
  for (int fn = 0; fn < 4; ++fn) wt3[fn] = w3S[fn * 16 + lr];
  #pragma unroll
  for (int cf = 0; cf < 2; ++cf) {
    f32x4 b2v = *(const f32x4*)&b2[e * CC + wv * 32 + cf * 16 + lg * 4];
    #pragma unroll
    for (int fn = 0; fn < 4; ++fn)
      #pragma unroll
      for (int r = 0; r < 4; ++r)
        oacc[cf][fn][r] = __builtin_fmaf(wt3[fn], b2v[r], oacc[cf][fn][r]);
  }
  #pragma unroll
  for (int fn = 0; fn < 4; ++fn) {
    const int row = lstart + fn * 16 + lr;
    unsigned char* po = Op3 + (size_t)row * 512;
    #pragma unroll
    for (int cf = 0; cf < 2; ++cf) {
      u32x2 pk;
      pk[0] = cvt_pk_bf16(oacc[cf][fn][0], oacc[cf][fn][1]);
      pk[1] = cvt_pk_bf16(oacc[cf][fn][2], oacc[cf][fn][3]);
      *(u32x2*)(po + (wv * 32 + cf * 16 + lg * 4) * 2) = pk;
    }
  }
}

// ---------- unscatter3: sum 3 bf16 rows per token -> out[b][c][n] ----------
__global__ __launch_bounds__(256) void unscatter3_k(
    const unsigned char* __restrict__ Op3, const unsigned* __restrict__ pos3,
    float* __restrict__ out) {
  __shared__ float lo[32 * 261];            // stride 261: conflict-free transpose
  __shared__ unsigned psf[96];
  const int tid = threadIdx.x;
  const int n0g = blockIdx.x * 32;
  const int b = n0g >> 15, n0 = n0g & (NN - 1);

  if (tid < 96) psf[tid] = pos3[(size_t)n0g * 3 + tid];
  __syncthreads();

  #pragma unroll
  for (int j = 0; j < 8; ++j) {
    const int row = j * 4 + (tid >> 6);
    const int c = (tid & 63) * 4;
    float a0 = 0.f, a1 = 0.f, a2 = 0.f, a3 = 0.f;
    #pragma unroll
    for (int s = 0; s < 3; ++s) {
      const unsigned r = psf[row * 3 + s];
      u32x2 v = *(const u32x2*)(Op3 + (size_t)r * 512 + c * 2);
      a0 += __builtin_bit_cast(float, v[0] << 16);
      a1 += __builtin_bit_cast(float, v[0] & 0xFFFF0000u);
      a2 += __builtin_bit_cast(float, v[1] << 16);
      a3 += __builtin_bit_cast(float, v[1] & 0xFFFF0000u);
    }
    lo[row * 261 + c + 0] = a0; lo[row * 261 + c + 1] = a1;
    lo[row * 261 + c + 2] = a2; lo[row * 261 + c + 3] = a3;
  }
  __syncthreads();

  const int noff = tid & 31, cq = tid >> 5;
  float* po = out + (size_t)b * CC * NN + n0 + noff;
  #pragma unroll
  for (int j2 = 0; j2 < 32; ++j2) {
    int c = cq * 32 + j2;
    po[(size_t)c * NN] = lo[noff * 261 + c];
  }
}

// ================================================================
// =============  BUCKET PATH (R6, proven fallback)  ==============
// ================================================================

__global__ __launch_bounds__(256) void gate_k(
    const float* __restrict__ x, const float* __restrict__ attn,
    const float* __restrict__ gate_w, const float* __restrict__ gate_b,
    unsigned* __restrict__ setid, float* __restrict__ wsel,
    unsigned* __restrict__ bhist) {
  __shared__ float gws[EE * CC];
  __shared__ unsigned hist[20];
  const int tid = threadIdx.x;
  const int blk = blockIdx.x;
  for (int i = tid; i < EE * CC; i += 256) gws[i] = gate_w[i];
  if (tid < 20) hist[tid] = 0;
  __syncthreads();

  const unsigned id = blk * 256 + tid;
  const int b = id >> 15, n = id & (NN - 1);
  const float* px = x + (size_t)b * CC * NN + n;
  float g[EE] = {0.f, 0.f, 0.f, 0.f, 0.f, 0.f};
  #pragma unroll 4
  for (int c = 0; c < CC; ++c) {
    float xv = px[(size_t)c * NN];
    #pragma unroll
    for (int e = 0; e < EE; ++e) g[e] = __builtin_fmaf(xv, gws[e * CC + c], g[e]);
  }
  float aw = attn[id];
  float m = -1e30f;
  #pragma unroll
  for (int e = 0; e < EE; ++e) { g[e] = (g[e] + gate_b[e]) * aw; m = fmaxf(m, g[e]); }
  float ex[EE], s = 0.f;
  #pragma unroll
  for (int e = 0; e < EE; ++e) { ex[e] = expf(g[e] - m); s += ex[e]; }
  int i1 = 0; float v1 = g[0];
  #pragma unroll
  for (int e = 1; e < EE; ++e) if (g[e] > v1) { v1 = g[e]; i1 = e; }
  int i2 = -1; float v2 = -3.4e38f;
  #pragma unroll
  for (int e = 0; e < EE; ++e) if (e != i1 && g[e] > v2) { v2 = g[e]; i2 = e; }
  int i3 = -1; float v3 = -3.4e38f;
  #pragma unroll
  for (int e = 0; e < EE; ++e) if (e != i1 && e != i2 && g[e] > v3) { v3 = g[e]; i3 = e; }
  const unsigned msk = (1u << i1) | (1u << i2) | (1u << i3);
  const unsigned bkt = M2B[msk];
  float inv = 1.f / s;
  int slot = 0;
  #pragma unroll
  for (int e = 0; e < EE; ++e)
    if ((msk >> e) & 1u) wsel[(size_t)id * 3 + (slot++)] = ex[e] * inv;
  setid[id] = bkt;
  atomicAdd(&hist[bkt], 1u);
  __syncthreads();
  if (tid < 20) bhist[blk * 20 + tid] = hist[tid];
}

__global__ void prefix_k(const unsigned* __restrict__ bhist, unsigned* __restrict__ bbase,
                         unsigned* __restrict__ desc) {
  __shared__ unsigned tot[20];
  __shared__ unsigned bb[21];
  __shared__ unsigned tcum[21];
  const int tid = threadIdx.x;
  if (tid < 20) {
    unsigned run = 0;
    for (int blk = 0; blk < 256; ++blk) {
      unsigned v = bhist[blk * 20 + tid];
      bbase[blk * 20 + tid] = run;
      run += v;
    }
    tot[tid] = run;
  }
  __syncthreads();
  if (tid == 0) {
    unsigned base = 0, tc = 0;
    for (int b = 0; b < 20; ++b) {
      bb[b] = base; tcum[b] = tc;
      unsigned tl = (tot[b] + 63) >> 6;
      tc += tl; base += tl << 6;
    }
    bb[20] = base; tcum[20] = tc;
  }
  __syncthreads();
  if (tid < 20) {
    unsigned b0 = bb[tid];
    for (int blk = 0; blk < 256; ++blk) bbase[blk * 20 + tid] += b0;
  }
  __syncthreads();
  const unsigned nt = tcum[20];
  for (int i = tid; i < NTILE_MAX; i += 256) {
    unsigned d;
    if ((unsigned)i < nt) {
      int b = 0;
      while (!((unsigned)i >= tcum[b] && (unsigned)i < tcum[b + 1])) ++b;
      d = ((unsigned)b << 16) | ((bb[b] >> 6) + ((unsigned)i - tcum[b]));
    } else {
      d = 0x003F0000u;
    }
    desc[i] = d;
  }
}

__global__ __launch_bounds__(256) void scatter_k(
    const unsigned* __restrict__ setid, const unsigned* __restrict__ bbase,
    const float* __restrict__ wsel,
    unsigned* __restrict__ pos, float* __restrict__ wp) {
  __shared__ unsigned wcnt[4][20];
  const int tid = threadIdx.x, lane = tid & 63, w = tid >> 6;
  const int blk = blockIdx.x;
  const unsigned id = blk * 256 + tid;
  const unsigned sid = setid[id];
  unsigned long long myb = 0;
  #pragma unroll
  for (int b = 0; b < 20; ++b) {
    unsigned long long bl = __ballot(sid == (unsigned)b);
    if (lane == 0) wcnt[w][b] = (unsigned)__builtin_popcountll(bl);
    if ((unsigned)b == sid) myb = bl;
  }
  __syncthreads();
  unsigned rank = 0;
  #pragma unroll
  for (int w2 = 0; w2 < 4; ++w2) if (w2 < w) rank += wcnt[w2][sid];
  rank += (unsigned)__builtin_popcountll(myb & ((1ull << lane) - 1ull));
  const unsigned p = bbase[blk * 20 + sid] + rank;
  pos[id] = p;
  #pragma unroll
  for (int s = 0; s < 3; ++s) wp[(size_t)p * 3 + s] = wsel[(size_t)id * 3 + s];
}

__global__ __launch_bounds__(256) void xpack_k(
    const float* __restrict__ x, const unsigned* __restrict__ pos,
    unsigned char* __restrict__ Xp) {
  __shared__ unsigned char lx[TT * 512];
  __shared__ unsigned posS[TT];
  const int tid = threadIdx.x, lane = tid & 63, wv = tid >> 6;
  const int n0g = blockIdx.x * TT;
  const int b = n0g >> 15, n0 = n0g & (NN - 1);

  if (tid < TT) posS[tid] = pos[n0g + tid];

  const float* px = x + (size_t)b * CC * NN + n0 + lane;
  #pragma unroll 1
  for (int c8 = 0; c8 < 8; ++c8) {
    float xv[8];
    #pragma unroll
    for (int j = 0; j < 8; ++j)
      xv[j] = px[(size_t)(wv * 64 + c8 * 8 + j) * NN];
    u32x4 pk;
    #pragma unroll
    for (int q = 0; q < 4; ++q) pk[q] = cvt_pk_bf16(xv[2 * q], xv[2 * q + 1]);
    *(u32x4*)(lx + lane * 512 + (wv * 64 + c8 * 8) * 2) = pk;
  }
  __syncthreads();

  #pragma unroll 1
  for (int r = 0; r < 16; ++r) {
    const int t = wv * 16 + r;
    const unsigned p = posS[t];
    u32x2 v = *(const u32x2*)(lx + t * 512 + lane * 8);
    *(u32x2*)(Xp + (size_t)p * 512 + (((unsigned)(lane * 8)) ^ (((unsigned)(p & 31)) << 4))) = v;
  }
}

__global__ __launch_bounds__(256, 2) void moe_main(
    const float* __restrict__ b1, const float* __restrict__ b2,
    const unsigned short* __restrict__ w1b, const unsigned short* __restrict__ w2b,
    const unsigned* __restrict__ desc, const float* __restrict__ wp,
    const unsigned char* __restrict__ Xp, float* __restrict__ Op) {
  __shared__ unsigned char xs[TT * CC * 2];
  __shared__ unsigned char hs[TT * 256 * 2];
  __shared__ float w3S[3 * TT];

  const unsigned d = desc[blockIdx.x];
  const unsigned bkt = d >> 16;
  if (bkt > 19) return;
  const int lstart = (int)(d & 0xFFFFu) << 6;

  const int tid  = threadIdx.x;
  const int lane = tid & 63;
  const int wv   = tid >> 6;
  const int lr   = lane & 15;
  const int lg   = lane >> 4;

  if (tid < 3 * TT) {
    int t = tid & 63, s = tid >> 6;
    w3S[s * 64 + t] = wp[(size_t)(lstart + t) * 3 + s];
  }

  {
    const unsigned char* src = Xp + (size_t)lstart * 512;
    #pragma unroll
    for (int it = 0; it < 8; ++it) {
      u32x4 v = *(const u32x4*)(src + it * 4096 + tid * 16);
      *(u32x4*)(xs + it * 4096 + tid * 16) = v;
    }
  }
  __syncthreads();

  f32x4 oacc[4][4];
  #pragma unroll
  for (int fm = 0; fm < 4; ++fm)
    #pragma unroll
    for (int fn = 0; fn < 4; ++fn) oacc[fm][fn] = (f32x4){0.f, 0.f, 0.f, 0.f};

  unsigned trowA[4], tswA[4];
  #pragma unroll
  for (int fn = 0; fn < 4; ++fn) {
    int t = fn * 16 + lr;
    trowA[fn] = (unsigned)t * 512u;
    tswA[fn]  = ((unsigned)(t & 31)) << 4;
  }

  #pragma unroll 1
  for (int xe = 0; xe < 3; ++xe) {
    const int e = CMB[bkt][xe];
    #pragma unroll 1
    for (int sc = 0; sc < 4; ++sc) {
      f32x4 hacc[4][4];
      #pragma unroll
      for (int fm = 0; fm < 4; ++fm)
        #pragma unroll
        for (int fn = 0; fn < 4; ++fn) hacc[fm][fn] = (f32x4){0.f, 0.f, 0.f, 0.f};
      const unsigned short* w1p =
          w1b + ((size_t)(e * HID + sc * 256 + wv * 64 + lr)) * CC + lg * 8;
      #pragma unroll
      for (int ks = 0; ks < 8; ++ks) {
        bf16x8 af[4], bxv[4];
        #pragma unroll
        for (int fm = 0; fm < 4; ++fm)
          af[fm] = *(const bf16x8*)(w1p + fm * 16 * CC + ks * 32);
        #pragma unroll
        for (int fn = 0; fn < 4; ++fn)
          bxv[fn] = *(const bf16x8*)(xs + trowA[fn] +
                                    (((unsigned)(ks * 64 + lg * 16)) ^ tswA[fn]));
        #pragma unroll
        for (int fn = 0; fn < 4; ++fn)
          #pragma unroll
          for (int fm = 0; fm < 4; ++fm)
            hacc[fm][fn] =
                __builtin_amdgcn_mfma_f32_16x16x32_bf16(af[fm], bxv[fn], hacc[fm][fn], 0, 0, 0);
      }
      {
        f32x4 b1v[4];
        #pragma unroll
        for (int fm = 0; fm < 4; ++fm)
          b1v[fm] = *(const f32x4*)&b1[e * HID + sc * 256 + wv * 64 + fm * 16 + lg * 4];
        #pragma unroll
        for (int fn = 0; fn < 4; ++fn) {
          float msk = w3S[xe * 64 + fn * 16 + lr];
          #pragma unroll
          for (int fm = 0; fm < 4; ++fm) {
            float gg[4];
            #pragma unroll
            for (int r = 0; r < 4; ++r)
              gg[r] = fast_gelu(hacc[fm][fn][r] + b1v[fm][r]) * msk;
            u32x2 pk;
            pk[0] = cvt_pk_bf16(gg[0], gg[1]);
            pk[1] = cvt_pk_bf16(gg[2], gg[3]);
            unsigned byteo = trowA[fn] +
                (((unsigned)((wv * 64 + fm * 16 + lg * 4) * 2)) ^ tswA[fn]);
            *(u32x2*)(hs + byteo) = pk;
          }
        }
      }
      __syncthreads();
      const unsigned short* w2p =
          w2b + ((size_t)(e * CC + wv * 64 + lr)) * HID + sc * 256 + lg * 8;
      #pragma unroll
      for (int ks = 0; ks < 8; ++ks) {
        bf16x8 am[4], bh[4];
        #pragma unroll
        for (int fm = 0; fm < 4; ++fm)
          am[fm] = *(const bf16x8*)(w2p + fm * 16 * HID + ks * 32);
        #pragma unroll
        for (int fn = 0; fn < 4; ++fn)
          bh[fn] = *(const bf16x8*)(hs + trowA[fn] +
                                    (((unsigned)(ks * 64 + lg * 16)) ^ tswA[fn]));
        #pragma unroll
        for (int fn = 0; fn < 4; ++fn)
          #pragma unroll
          for (int fm = 0; fm < 4; ++fm)
            oacc[fm][fn] =
                __builtin_amdgcn_mfma_f32_16x16x32_bf16(am[fm], bh[fn], oacc[fm][fn], 0, 0, 0);
      }
      __syncthreads();
    }
  }

  #pragma unroll
  for (int xe = 0; xe < 3; ++xe) {
    const int e = CMB[bkt][xe];
    float msk[4];
    #pragma unroll
    for (int fn = 0; fn < 4; ++fn) msk[fn] = w3S[xe * 64 + fn * 16 + lr];
    #pragma unroll
    for (int fm = 0; fm < 4; ++fm) {
      f32x4 b2v = *(const f32x4*)&b2[e * CC + wv * 64 + fm * 16 + lg * 4];
      #pragma unroll
      for (int fn = 0; fn < 4; ++fn)
        #pragma unroll
        for (int r = 0; r < 4; ++r)
          oacc[fm][fn][r] = __builtin_fmaf(msk[fn], b2v[r], oacc[fm][fn][r]);
    }
  }
  #pragma unroll
  for (int fn = 0; fn < 4; ++fn) {
    float* po = Op + (size_t)(lstart + fn * 16 + lr) * CC;
    #pragma unroll
    for (int fm = 0; fm < 4; ++fm)
      *(f32x4*)(po + wv * 64 + fm * 16 + lg * 4) = oacc[fm][fn];
  }
}

__global__ __launch_bounds__(256) void unscatter_k(
    const float* __restrict__ Op, const unsigned* __restrict__ pos,
    float* __restrict__ out) {
  __shared__ float lo[32 * 261];
  __shared__ unsigned posS[32];
  const int tid = threadIdx.x;
  const int n0g = blockIdx.x * 32;
  const int b = n0g >> 15, n0 = n0g & (NN - 1);

  if (tid < 32) posS[tid] = pos[n0g + tid];
  __syncthreads();

  #pragma unroll
  for (int j = 0; j < 8; ++j) {
    int fidx = j * 1024 + tid * 4;
    int row = fidx >> 8, c = fidx & 255;
    f32x4 v = *(const f32x4*)(Op + (size_t)posS[row] * CC + c);
    #pragma unroll
    for (int i = 0; i < 4; ++i) lo[row * 261 + c + i] = v[i];
  }
  __syncthreads();

  const int noff = tid & 31, cq = tid >> 5;
  float* po = out + (size_t)b * CC * NN + n0 + noff;
  #pragma unroll
  for (int j2 = 0; j2 < 32; ++j2) {
    int c = cq * 32 + j2;
    po[(size_t)c * NN] = lo[noff * 261 + c];
  }
}

// ================================================================

extern "C" void kernel_launch(void* const* d_in, const int* in_sizes, int n_in,
                              void* d_out, int out_size, void* d_ws, size_t ws_size,
                              hipStream_t stream) {
  const float* x      = (const float*)d_in[0];
  const float* attn   = (const float*)d_in[1];
  const float* gate_w = (const float*)d_in[2];
  const float* gate_b = (const float*)d_in[3];
  const float* w1     = (const float*)d_in[4];
  const float* b1     = (const float*)d_in[5];
  const float* w2     = (const float*)d_in[6];
  const float* b2     = (const float*)d_in[7];
  float* out = (float*)d_out;

  unsigned char* ws = (unsigned char*)d_ws;
  // shared head
  unsigned short* w1b  = (unsigned short*)(ws);             // 3,145,728
  unsigned short* w2b  = (unsigned short*)(ws + 3145728);   // -> 6,291,456
  unsigned*       setid= (unsigned*)(ws + 6291456);         // -> 6,553,600
  float*          wsel = (float*)(ws + 6553600);            // -> 7,340,032
  // bucket-path tail (aliases expert-major tail; exclusive)
  unsigned*       bhist= (unsigned*)(ws + 7340032);         // 20,480
  unsigned*       bbase= (unsigned*)(ws + 7360512);         // 20,480
  unsigned*       desc = (unsigned*)(ws + 7381120);         // 4,224
  unsigned*       pos  = (unsigned*)(ws + 7385344);         // 262,144
  float*          wp   = (float*)(ws + 7647488);            // 801,792
  unsigned char*  Xp   = (unsigned char*)(ws + 8449280);    // 34,209,792
  float*          Op   = (float*)(ws + 42659072);           // 68,419,584
  const size_t need_bucket = 111078656;
  // expert-major tail (starts after wsel)
  unsigned*       ehist = (unsigned*)(ws + 7360512);        // 24,576
  unsigned*       ebase = (unsigned*)(ws + 7385088);        // 24,576
  unsigned*       desc3 = (unsigned*)(ws + 7409664);        // 26,624
  unsigned*       tlist3= (unsigned*)(ws + 7436288);        // 787,968
  float*          wp3   = (float*)(ws + 8224256);           // 787,968
  unsigned*       pos3  = (unsigned*)(ws + 9012224);        // 786,432
  unsigned char*  Xp3   = (unsigned char*)(ws + 9798656);   // 33,554,432
  unsigned char*  Op3   = (unsigned char*)(ws + 43353088);  // 100,859,904
  const size_t need3 = 144212992;

  wconv<<<(EE * HID * CC) / 256, 256, 0, stream>>>(w1, w2, w1b, w2b);
  if (ws_size >= need3) {
    gatepack_k<<<NTOK / TT, 256, 0, stream>>>(x, attn, gate_w, gate_b, setid, wsel, ehist, Xp3);
    prefix3_k<<<1, 256, 0, stream>>>(ehist, ebase, desc3, tlist3, wp3);
    scatter3_k<<<NTOK / 64, 64, 0, stream>>>(setid, ebase, wsel, tlist3, wp3, pos3);
    moe_main3<<<NT3MAX, 512, 0, stream>>>(b1, b2, w1b, w2b, desc3, tlist3, wp3, Xp3, Op3);
    unscatter3_k<<<NTOK / 32, 256, 0, stream>>>(Op3, pos3, out);
  } else {
    gate_k<<<NTOK / 256, 256, 0, stream>>>(x, attn, gate_w, gate_b, setid, wsel, bhist);
    prefix_k<<<1, 256, 0, stream>>>(bhist, bbase, desc);
    scatter_k<<<NTOK / 256, 256, 0, stream>>>(setid, bbase, wsel, pos, wp);
    xpack_k<<<NTOK / TT, 256, 0, stream>>>(x, pos, Xp);
    moe_main<<<NTILE_MAX, 256, 0, stream>>>(b1, b2, w1b, w2b, desc, wp, Xp, Op);
    unscatter_k<<<NTOK / 32, 256, 0, stream>>>(Op, pos, out);
  }
}